// Round 6
// baseline (530.715 us; speedup 1.0000x reference)
//
#include <hip/hip_runtime.h>
#include <cstddef>

constexpr int NN    = 8192;
constexpr int DIN   = 1024;
constexpr int DMID  = 256;
constexpr int DEMB  = 64;
constexpr int NEDGE = 65536;

typedef __attribute__((ext_vector_type(8))) short bf16x8;
typedef __attribute__((ext_vector_type(4))) float f32x4;
#define MFMA16(a, b, c) __builtin_amdgcn_mfma_f32_16x16x32_bf16((a), (b), (c), 0, 0, 0)

__device__ __forceinline__ unsigned short bf16_rne(float x) {
  unsigned u = __float_as_uint(x);
  return (unsigned short)((u + 0x7FFFu + ((u >> 16) & 1u)) >> 16);
}
__device__ __forceinline__ float bf16_tof(unsigned short h) {
  return __uint_as_float((unsigned)h << 16);
}

// ---------------- prep: W1T/W2T transpose+round, plus edge histogram ----------------
constexpr int WCONV_BLOCKS = (DMID * DIN + DEMB * DMID) / 256;   // 1088
__global__ __launch_bounds__(256) void prep_kernel(const float* __restrict__ W1,
                                                   const float* __restrict__ W2,
                                                   unsigned short* __restrict__ W1b,
                                                   unsigned short* __restrict__ W2b,
                                                   const int* __restrict__ edst,
                                                   int* __restrict__ counts)
{
  int b = blockIdx.x;
  if (b < WCONV_BLOCKS) {
    int idx = b * 256 + threadIdx.x;
    if (idx < DMID * DIN) {                  // W1T [256][1024]
      int n = idx >> 10, k = idx & 1023;
      W1b[idx] = bf16_rne(W1[k * DMID + n]);
    } else {                                 // W2T [64][256]
      int t = idx - DMID * DIN;
      int n = t >> 8, k = t & 255;
      W2b[t] = bf16_rne(W2[k * DEMB + n]);
    }
  } else {
    int e = (b - WCONV_BLOCKS) * 256 + threadIdx.x;
    atomicAdd(&counts[edst[e]], 1);
  }
}

// ---------------- CSR build: scan + scatter ----------------
__global__ __launch_bounds__(256) void scan_kernel(const int* __restrict__ counts,
                                                   int* __restrict__ row_start)
{
  __shared__ int sums[256];
  const int t = threadIdx.x;
  int local[32];
  int s = 0;
#pragma unroll
  for (int i = 0; i < 32; ++i) { local[i] = counts[t * 32 + i]; s += local[i]; }
  sums[t] = s;
  __syncthreads();
  for (int off = 1; off < 256; off <<= 1) {
    int v = (t >= off) ? sums[t - off] : 0;
    __syncthreads();
    sums[t] += v;
    __syncthreads();
  }
  int base = (t == 0) ? 0 : sums[t - 1];
#pragma unroll
  for (int i = 0; i < 32; ++i) { row_start[t * 32 + i] = base; base += local[i]; }
  if (t == 255) row_start[NN] = base;
}

__global__ __launch_bounds__(256) void scatter_kernel(
    const int* __restrict__ src, const float* __restrict__ val,
    const int* __restrict__ dst, const int* __restrict__ row_start,
    int* __restrict__ cursor, int* __restrict__ csr_src, float* __restrict__ csr_val)
{
  int e = blockIdx.x * 256 + threadIdx.x;
  int d = dst[e];
  int pos = row_start[d] + atomicAdd(&cursor[d], 1);
  csr_src[pos] = src[e];
  csr_val[pos] = val[e];
}

// ---------------- GEMM1: G1 = bf16(X @ W1); X read once, full-N tile ----------------
__global__ __launch_bounds__(256) void gemm1_kernel(
    const float* __restrict__ X, const unsigned short* __restrict__ W1b,
    unsigned short* __restrict__ G1)
{
  const int lane = threadIdx.x & 63;
  const int wave = threadIdx.x >> 6;
  const int m0 = blockIdx.x * 64 + wave * 16;
  const int rl = lane & 15;
  const int kq = (lane >> 4) * 8;
  f32x4 zero = {0.f, 0.f, 0.f, 0.f};
  f32x4 acc[16];
#pragma unroll
  for (int ns = 0; ns < 16; ++ns) acc[ns] = zero;

  for (int s = 0; s < DIN / 32; ++s) {
    const int kb = s * 32 + kq;
    const float* xp = X + (size_t)(m0 + rl) * DIN + kb;
    float4 x0 = *(const float4*)xp;
    float4 x1 = *(const float4*)(xp + 4);
    bf16x8 ah;
    ah[0] = (short)bf16_rne(x0.x); ah[1] = (short)bf16_rne(x0.y);
    ah[2] = (short)bf16_rne(x0.z); ah[3] = (short)bf16_rne(x0.w);
    ah[4] = (short)bf16_rne(x1.x); ah[5] = (short)bf16_rne(x1.y);
    ah[6] = (short)bf16_rne(x1.z); ah[7] = (short)bf16_rne(x1.w);
#pragma unroll
    for (int ns = 0; ns < 16; ++ns) {
      bf16x8 bh = *(const bf16x8*)(W1b + (size_t)(ns * 16 + rl) * DIN + kb);
      acc[ns] = MFMA16(ah, bh, acc[ns]);
    }
  }
  const int rq = (lane >> 4) * 4;
#pragma unroll
  for (int ns = 0; ns < 16; ++ns)
#pragma unroll
    for (int r = 0; r < 4; ++r)
      G1[(size_t)(m0 + rq + r) * DMID + ns * 16 + rl] = bf16_rne(acc[ns][r]);
}

// ---------------- spmm1: H1b = bf16(relu(spmm(G1))), bf16 gather ----------------
__global__ __launch_bounds__(256) void spmm1_kernel(
    const unsigned short* __restrict__ G1, const int* __restrict__ row_start,
    const int* __restrict__ csr_src, const float* __restrict__ csr_val,
    unsigned short* __restrict__ Hb)
{
  const int lane = threadIdx.x & 63;
  const int wave = threadIdx.x >> 6;
  const int r = blockIdx.x * 4 + wave;
  const int e0 = row_start[r];
  const int e1 = row_start[r + 1];
  const int c = lane * 4;
  float4 acc = make_float4(0.f, 0.f, 0.f, 0.f);
  for (int e = e0; e < e1; ++e) {
    const int s   = csr_src[e];
    const float v = csr_val[e];
    ushort4 h = *(const ushort4*)(G1 + (size_t)s * DMID + c);
    acc.x = fmaf(v, bf16_tof(h.x), acc.x);
    acc.y = fmaf(v, bf16_tof(h.y), acc.y);
    acc.z = fmaf(v, bf16_tof(h.z), acc.z);
    acc.w = fmaf(v, bf16_tof(h.w), acc.w);
  }
  ushort4 h;
  h.x = bf16_rne(fmaxf(acc.x, 0.f));
  h.y = bf16_rne(fmaxf(acc.y, 0.f));
  h.z = bf16_rne(fmaxf(acc.z, 0.f));
  h.w = bf16_rne(fmaxf(acc.w, 0.f));
  *(ushort4*)(Hb + (size_t)r * DMID + c) = h;
}

// ---------------- GEMM2: E1 = H1b @ W2 ----------------
__global__ __launch_bounds__(256) void gemm2_kernel(
    const unsigned short* __restrict__ Ab, const unsigned short* __restrict__ W2b,
    float* __restrict__ E1)
{
  const int lane = threadIdx.x & 63;
  const int wave = threadIdx.x >> 6;
  const int m0 = blockIdx.x * 64 + wave * 16;
  const int rl = lane & 15;
  const int kq = (lane >> 4) * 8;
  f32x4 zero = {0.f, 0.f, 0.f, 0.f};
  f32x4 acc[4] = {zero, zero, zero, zero};
  for (int s = 0; s < DMID / 32; ++s) {
    const int kb = s * 32 + kq;
    bf16x8 ah = *(const bf16x8*)(Ab + (size_t)(m0 + rl) * DMID + kb);
#pragma unroll
    for (int ns = 0; ns < 4; ++ns) {
      bf16x8 bh = *(const bf16x8*)(W2b + (size_t)(ns * 16 + rl) * DMID + kb);
      acc[ns] = MFMA16(ah, bh, acc[ns]);
    }
  }
  const int rq = (lane >> 4) * 4;
#pragma unroll
  for (int ns = 0; ns < 4; ++ns)
#pragma unroll
    for (int r = 0; r < 4; ++r)
      E1[(size_t)(m0 + rq + r) * DEMB + ns * 16 + rl] = acc[ns][r];
}

// ---------------- spmm2: EmbH = bf16(spmm(E1)); sq from ROUNDED value ----------------
__global__ __launch_bounds__(256) void spmm2_kernel(
    const float* __restrict__ H, const int* __restrict__ row_start,
    const int* __restrict__ csr_src, const float* __restrict__ csr_val,
    unsigned short* __restrict__ EmbH, float* __restrict__ sqv)
{
  const int lane = threadIdx.x & 63;
  const int wave = threadIdx.x >> 6;
  const int r = blockIdx.x * 4 + wave;
  const int e0 = row_start[r];
  const int e1 = row_start[r + 1];
  float acc = 0.f;
  for (int e = e0; e < e1; ++e)
    acc = fmaf(csr_val[e], H[(size_t)csr_src[e] * DEMB + lane], acc);
  unsigned short h = bf16_rne(acc);
  EmbH[(size_t)r * DEMB + lane] = h;
  float hf = bf16_tof(h);              // sq computed from stored bf16 so dist_ii ~ 0
  float sq = hf * hf;
#pragma unroll
  for (int off = 32; off; off >>= 1) sq += __shfl_xor(sq, off, 64);
  if (lane == 0) sqv[r] = sq;
}

// ---------------- shared 64x64 tile: acc[ms][ns] = Emb_i . Emb_j (K=64) ----------------
__device__ __forceinline__ void dist_tile_hh(
    const unsigned short* __restrict__ EH, int ibase, int jbase, int lane,
    f32x4 (&acc)[4][4])
{
  const int rl = lane & 15;
  const int kq = (lane >> 4) * 8;
#pragma unroll
  for (int s = 0; s < 2; ++s) {
    const int kb = s * 32 + kq;
    bf16x8 a[4], b[4];
#pragma unroll
    for (int t = 0; t < 4; ++t) {
      a[t] = *(const bf16x8*)(EH + (size_t)(ibase + t * 16 + rl) * DEMB + kb);
      b[t] = *(const bf16x8*)(EH + (size_t)(jbase + t * 16 + rl) * DEMB + kb);
    }
#pragma unroll
    for (int ms = 0; ms < 4; ++ms)
#pragma unroll
      for (int ns = 0; ns < 4; ++ns)
        acc[ms][ns] = MFMA16(a[ms], b[ns], acc[ms][ns]);
  }
}

// ---------------- pass1: symmetric row sums (upper-triangle blocks only) ----------------
__global__ __launch_bounds__(256) void rowsum_sym_kernel(
    const unsigned short* __restrict__ EH, const float* __restrict__ sq,
    float* __restrict__ rowsum)
{
  const int bi = blockIdx.y, bj = blockIdx.x;
  if (bj < bi) return;
  const int lane = threadIdx.x & 63;
  const int wave = threadIdx.x >> 6;
  const int wr = wave >> 1, wc = wave & 1;
  const int ibase = bi * 128 + wr * 64;
  const int jbase = bj * 128 + wc * 64;
  const int rl = lane & 15;
  const int rq = (lane >> 4) * 4;

  f32x4 zero = {0.f, 0.f, 0.f, 0.f};
  f32x4 acc[4][4];
#pragma unroll
  for (int ms = 0; ms < 4; ++ms)
#pragma unroll
    for (int ns = 0; ns < 4; ++ns) acc[ms][ns] = zero;
  dist_tile_hh(EH, ibase, jbase, lane, acc);

  float si[4][4], sj[4];
#pragma unroll
  for (int ms = 0; ms < 4; ++ms)
#pragma unroll
    for (int r = 0; r < 4; ++r) si[ms][r] = sq[ibase + ms * 16 + rq + r];
#pragma unroll
  for (int ns = 0; ns < 4; ++ns) sj[ns] = sq[jbase + ns * 16 + rl];

  float rs[4][4] = {};   // row partials (this lane's rl-slice)
  float cs[4]    = {};   // col partials (this lane's column, over its 4 quad-rows)
#pragma unroll
  for (int ms = 0; ms < 4; ++ms)
#pragma unroll
    for (int ns = 0; ns < 4; ++ns)
#pragma unroll
      for (int r = 0; r < 4; ++r) {
        float v = __expf(fmaf(2.f, acc[ms][ns][r], -si[ms][r] - sj[ns]));
        rs[ms][r] += v;
        cs[ns]    += v;
      }

  // row sums: reduce across rl within quad
#pragma unroll
  for (int ms = 0; ms < 4; ++ms)
#pragma unroll
    for (int r = 0; r < 4; ++r) {
      float v = rs[ms][r];
      v += __shfl_xor(v, 1, 64);
      v += __shfl_xor(v, 2, 64);
      v += __shfl_xor(v, 4, 64);
      v += __shfl_xor(v, 8, 64);
      if (rl == 0) atomicAdd(&rowsum[ibase + ms * 16 + rq + r], v);
    }

  // col sums (transposed contributions) only for off-diagonal blocks
  if (bi != bj) {
#pragma unroll
    for (int ns = 0; ns < 4; ++ns) {
      float v = cs[ns];
      v += __shfl_xor(v, 16, 64);
      v += __shfl_xor(v, 32, 64);
      if (lane < 16) atomicAdd(&rowsum[jbase + ns * 16 + rl], v);
    }
  }
}

// ---------------- pass2: full grid, recompute e, fully coalesced stores ----------------
__global__ __launch_bounds__(256) void dist_write_kernel(
    const unsigned short* __restrict__ EH, const float* __restrict__ sq,
    const float* __restrict__ rowsum, float* __restrict__ out)
{
  const int lane = threadIdx.x & 63;
  const int wave = threadIdx.x >> 6;
  const int wr = wave >> 1, wc = wave & 1;
  const int ibase = blockIdx.y * 128 + wr * 64;
  const int jbase = blockIdx.x * 128 + wc * 64;
  const int rl = lane & 15;
  const int rq = (lane >> 4) * 4;

  f32x4 zero = {0.f, 0.f, 0.f, 0.f};
  f32x4 acc[4][4];
#pragma unroll
  for (int ms = 0; ms < 4; ++ms)
#pragma unroll
    for (int ns = 0; ns < 4; ++ns) acc[ms][ns] = zero;
  dist_tile_hh(EH, ibase, jbase, lane, acc);

  float si[4][4], ri[4][4], sj[4];
#pragma unroll
  for (int ms = 0; ms < 4; ++ms)
#pragma unroll
    for (int r = 0; r < 4; ++r) {
      const int i = ibase + ms * 16 + rq + r;
      si[ms][r] = sq[i];
      ri[ms][r] = 1.f / rowsum[i];
    }
#pragma unroll
  for (int ns = 0; ns < 4; ++ns) sj[ns] = sq[jbase + ns * 16 + rl];

#pragma unroll
  for (int ms = 0; ms < 4; ++ms)
#pragma unroll
    for (int r = 0; r < 4; ++r) {
      const size_t row = (size_t)(ibase + ms * 16 + rq + r) * NN;
#pragma unroll
      for (int ns = 0; ns < 4; ++ns) {
        float e = __expf(fmaf(2.f, acc[ms][ns][r], -si[ms][r] - sj[ns]));
        out[row + jbase + ns * 16 + rl] = fmaf(e, ri[ms][r], 1e-10f);
      }
    }
}

// ---------------- launch ----------------
extern "C" void kernel_launch(void* const* d_in, const int* in_sizes, int n_in,
                              void* d_out, int out_size, void* d_ws, size_t ws_size,
                              hipStream_t stream)
{
  const float* X  = (const float*)d_in[0];
  const float* W1 = (const float*)d_in[1];
  const float* W2 = (const float*)d_in[2];
  const float* ev = (const float*)d_in[3];
  const int* esrc = (const int*)d_in[4];
  const int* edst = (const int*)d_in[5];
  float* out = (float*)d_out;

  char* p = (char*)d_ws;
  auto alloc = [&](size_t bytes) { char* q = p; p += (bytes + 255) & ~(size_t)255; return q; };

  // zero block first (single memset): counts, cursor, rowsum
  int*   counts    = (int*)alloc(NN * 4);
  int*   cursor    = (int*)alloc(NN * 4);
  float* rowsum    = (float*)alloc(NN * 4);
  int*   row_start = (int*)alloc((NN + 1) * 4);
  int*   csr_src   = (int*)alloc(NEDGE * 4);
  float* csr_val   = (float*)alloc(NEDGE * 4);
  float* sqv       = (float*)alloc(NN * 4);
  float* E1        = (float*)alloc((size_t)NN * DEMB * 4);
  unsigned short* W1b  = (unsigned short*)alloc((size_t)DMID * DIN * 2);
  unsigned short* W2b  = (unsigned short*)alloc((size_t)DEMB * DMID * 2);
  unsigned short* G1   = (unsigned short*)alloc((size_t)NN * DMID * 2);
  unsigned short* H1b  = (unsigned short*)alloc((size_t)NN * DMID * 2);
  unsigned short* EmbH = (unsigned short*)alloc((size_t)NN * DEMB * 2);

  hipMemsetAsync(d_ws, 0, (size_t)3 * NN * 4, stream);

  prep_kernel<<<WCONV_BLOCKS + NEDGE / 256, 256, 0, stream>>>(W1, W2, W1b, W2b, edst, counts);
  scan_kernel<<<1, 256, 0, stream>>>(counts, row_start);
  scatter_kernel<<<NEDGE / 256, 256, 0, stream>>>(esrc, ev, edst, row_start, cursor,
                                                  csr_src, csr_val);

  gemm1_kernel<<<NN / 64, 256, 0, stream>>>(X, W1b, G1);
  spmm1_kernel<<<NN / 4, 256, 0, stream>>>(G1, row_start, csr_src, csr_val, H1b);
  gemm2_kernel<<<NN / 64, 256, 0, stream>>>(H1b, W2b, E1);
  spmm2_kernel<<<NN / 4, 256, 0, stream>>>(E1, row_start, csr_src, csr_val, EmbH, sqv);

  rowsum_sym_kernel<<<dim3(NN / 128, NN / 128), 256, 0, stream>>>(EmbH, sqv, rowsum);
  dist_write_kernel<<<dim3(NN / 128, NN / 128), 256, 0, stream>>>(EmbH, sqv, rowsum, out);
}

// Round 7
// 457.614 us; speedup vs baseline: 1.1597x; 1.1597x over previous
//
#include <hip/hip_runtime.h>
#include <cstddef>

constexpr int NN    = 8192;
constexpr int DIN   = 1024;
constexpr int DMID  = 256;
constexpr int DEMB  = 64;
constexpr int NEDGE = 65536;

typedef __attribute__((ext_vector_type(8))) short bf16x8;
typedef __attribute__((ext_vector_type(4))) float f32x4;
#define MFMA16(a, b, c) __builtin_amdgcn_mfma_f32_16x16x32_bf16((a), (b), (c), 0, 0, 0)

__device__ __forceinline__ unsigned short bf16_rne(float x) {
  unsigned u = __float_as_uint(x);
  return (unsigned short)((u + 0x7FFFu + ((u >> 16) & 1u)) >> 16);
}
__device__ __forceinline__ float bf16_tof(unsigned short h) {
  return __uint_as_float((unsigned)h << 16);
}

// ---------------- prep: W1T/W2T transpose+round, plus edge histogram ----------------
constexpr int WCONV_BLOCKS = (DMID * DIN + DEMB * DMID) / 256;   // 1088
__global__ __launch_bounds__(256) void prep_kernel(const float* __restrict__ W1,
                                                   const float* __restrict__ W2,
                                                   unsigned short* __restrict__ W1b,
                                                   unsigned short* __restrict__ W2b,
                                                   const int* __restrict__ edst,
                                                   int* __restrict__ counts)
{
  int b = blockIdx.x;
  if (b < WCONV_BLOCKS) {
    int idx = b * 256 + threadIdx.x;
    if (idx < DMID * DIN) {                  // W1T [256][1024]
      int n = idx >> 10, k = idx & 1023;
      W1b[idx] = bf16_rne(W1[k * DMID + n]);
    } else {                                 // W2T [64][256]
      int t = idx - DMID * DIN;
      int n = t >> 8, k = t & 255;
      W2b[t] = bf16_rne(W2[k * DEMB + n]);
    }
  } else {
    int e = (b - WCONV_BLOCKS) * 256 + threadIdx.x;
    atomicAdd(&counts[edst[e]], 1);
  }
}

// ---------------- CSR build: scan + scatter ----------------
__global__ __launch_bounds__(256) void scan_kernel(const int* __restrict__ counts,
                                                   int* __restrict__ row_start)
{
  __shared__ int sums[256];
  const int t = threadIdx.x;
  int local[32];
  int s = 0;
#pragma unroll
  for (int i = 0; i < 32; ++i) { local[i] = counts[t * 32 + i]; s += local[i]; }
  sums[t] = s;
  __syncthreads();
  for (int off = 1; off < 256; off <<= 1) {
    int v = (t >= off) ? sums[t - off] : 0;
    __syncthreads();
    sums[t] += v;
    __syncthreads();
  }
  int base = (t == 0) ? 0 : sums[t - 1];
#pragma unroll
  for (int i = 0; i < 32; ++i) { row_start[t * 32 + i] = base; base += local[i]; }
  if (t == 255) row_start[NN] = base;
}

__global__ __launch_bounds__(256) void scatter_kernel(
    const int* __restrict__ src, const float* __restrict__ val,
    const int* __restrict__ dst, const int* __restrict__ row_start,
    int* __restrict__ cursor, int* __restrict__ csr_src, float* __restrict__ csr_val)
{
  int e = blockIdx.x * 256 + threadIdx.x;
  int d = dst[e];
  int pos = row_start[d] + atomicAdd(&cursor[d], 1);
  csr_src[pos] = src[e];
  csr_val[pos] = val[e];
}

// ---------------- GEMM1: G1 = bf16(X @ W1); R5 tiling (512 blocks), bf16 out ----------
__global__ __launch_bounds__(256) void gemm1_kernel(
    const float* __restrict__ X, const unsigned short* __restrict__ W1b,
    unsigned short* __restrict__ G1)
{
  const int lane = threadIdx.x & 63;
  const int wave = threadIdx.x >> 6;
  const int m0 = blockIdx.y * 64 + wave * 16;
  const int n0 = blockIdx.x * 64;
  const int rl = lane & 15;
  const int kq = (lane >> 4) * 8;
  f32x4 zero = {0.f, 0.f, 0.f, 0.f};
  f32x4 acc[4] = {zero, zero, zero, zero};
  for (int s = 0; s < DIN / 32; ++s) {
    const int kb = s * 32 + kq;
    const float* xp = X + (size_t)(m0 + rl) * DIN + kb;
    float4 x0 = *(const float4*)xp;
    float4 x1 = *(const float4*)(xp + 4);
    bf16x8 ah;
    ah[0] = (short)bf16_rne(x0.x); ah[1] = (short)bf16_rne(x0.y);
    ah[2] = (short)bf16_rne(x0.z); ah[3] = (short)bf16_rne(x0.w);
    ah[4] = (short)bf16_rne(x1.x); ah[5] = (short)bf16_rne(x1.y);
    ah[6] = (short)bf16_rne(x1.z); ah[7] = (short)bf16_rne(x1.w);
#pragma unroll
    for (int ns = 0; ns < 4; ++ns) {
      bf16x8 bh = *(const bf16x8*)(W1b + (size_t)(n0 + ns * 16 + rl) * DIN + kb);
      acc[ns] = MFMA16(ah, bh, acc[ns]);
    }
  }
  const int rq = (lane >> 4) * 4;
#pragma unroll
  for (int ns = 0; ns < 4; ++ns)
#pragma unroll
    for (int r = 0; r < 4; ++r)
      G1[(size_t)(m0 + rq + r) * DMID + n0 + ns * 16 + rl] = bf16_rne(acc[ns][r]);
}

// ---------------- spmm1: H1b = bf16(relu(spmm(G1))), bf16 gather ----------------
__global__ __launch_bounds__(256) void spmm1_kernel(
    const unsigned short* __restrict__ G1, const int* __restrict__ row_start,
    const int* __restrict__ csr_src, const float* __restrict__ csr_val,
    unsigned short* __restrict__ Hb)
{
  const int lane = threadIdx.x & 63;
  const int wave = threadIdx.x >> 6;
  const int r = blockIdx.x * 4 + wave;
  const int e0 = row_start[r];
  const int e1 = row_start[r + 1];
  const int c = lane * 4;
  float4 acc = make_float4(0.f, 0.f, 0.f, 0.f);
  for (int e = e0; e < e1; ++e) {
    const int s   = csr_src[e];
    const float v = csr_val[e];
    ushort4 h = *(const ushort4*)(G1 + (size_t)s * DMID + c);
    acc.x = fmaf(v, bf16_tof(h.x), acc.x);
    acc.y = fmaf(v, bf16_tof(h.y), acc.y);
    acc.z = fmaf(v, bf16_tof(h.z), acc.z);
    acc.w = fmaf(v, bf16_tof(h.w), acc.w);
  }
  ushort4 h;
  h.x = bf16_rne(fmaxf(acc.x, 0.f));
  h.y = bf16_rne(fmaxf(acc.y, 0.f));
  h.z = bf16_rne(fmaxf(acc.z, 0.f));
  h.w = bf16_rne(fmaxf(acc.w, 0.f));
  *(ushort4*)(Hb + (size_t)r * DMID + c) = h;
}

// ---------------- GEMM2: E1 = H1b @ W2 ----------------
__global__ __launch_bounds__(256) void gemm2_kernel(
    const unsigned short* __restrict__ Ab, const unsigned short* __restrict__ W2b,
    float* __restrict__ E1)
{
  const int lane = threadIdx.x & 63;
  const int wave = threadIdx.x >> 6;
  const int m0 = blockIdx.x * 64 + wave * 16;
  const int rl = lane & 15;
  const int kq = (lane >> 4) * 8;
  f32x4 zero = {0.f, 0.f, 0.f, 0.f};
  f32x4 acc[4] = {zero, zero, zero, zero};
  for (int s = 0; s < DMID / 32; ++s) {
    const int kb = s * 32 + kq;
    bf16x8 ah = *(const bf16x8*)(Ab + (size_t)(m0 + rl) * DMID + kb);
#pragma unroll
    for (int ns = 0; ns < 4; ++ns) {
      bf16x8 bh = *(const bf16x8*)(W2b + (size_t)(ns * 16 + rl) * DMID + kb);
      acc[ns] = MFMA16(ah, bh, acc[ns]);
    }
  }
  const int rq = (lane >> 4) * 4;
#pragma unroll
  for (int ns = 0; ns < 4; ++ns)
#pragma unroll
    for (int r = 0; r < 4; ++r)
      E1[(size_t)(m0 + rq + r) * DEMB + ns * 16 + rl] = acc[ns][r];
}

// ---------------- spmm2: EmbH = bf16(spmm(E1)); sq from ROUNDED value ----------------
__global__ __launch_bounds__(256) void spmm2_kernel(
    const float* __restrict__ H, const int* __restrict__ row_start,
    const int* __restrict__ csr_src, const float* __restrict__ csr_val,
    unsigned short* __restrict__ EmbH, float* __restrict__ sqv)
{
  const int lane = threadIdx.x & 63;
  const int wave = threadIdx.x >> 6;
  const int r = blockIdx.x * 4 + wave;
  const int e0 = row_start[r];
  const int e1 = row_start[r + 1];
  float acc = 0.f;
  for (int e = e0; e < e1; ++e)
    acc = fmaf(csr_val[e], H[(size_t)csr_src[e] * DEMB + lane], acc);
  unsigned short h = bf16_rne(acc);
  EmbH[(size_t)r * DEMB + lane] = h;
  float hf = bf16_tof(h);              // sq computed from stored bf16 so dist_ii ~ 0
  float sq = hf * hf;
#pragma unroll
  for (int off = 32; off; off >>= 1) sq += __shfl_xor(sq, off, 64);
  if (lane == 0) sqv[r] = sq;
}

// ---------------- shared 64x64 tile: acc[ms][ns] = Emb_i . Emb_j (K=64) ----------------
__device__ __forceinline__ void dist_tile_hh(
    const unsigned short* __restrict__ EH, int ibase, int jbase, int lane,
    f32x4 (&acc)[4][4])
{
  const int rl = lane & 15;
  const int kq = (lane >> 4) * 8;
#pragma unroll
  for (int s = 0; s < 2; ++s) {
    const int kb = s * 32 + kq;
    bf16x8 a[4], b[4];
#pragma unroll
    for (int t = 0; t < 4; ++t) {
      a[t] = *(const bf16x8*)(EH + (size_t)(ibase + t * 16 + rl) * DEMB + kb);
      b[t] = *(const bf16x8*)(EH + (size_t)(jbase + t * 16 + rl) * DEMB + kb);
    }
#pragma unroll
    for (int ms = 0; ms < 4; ++ms)
#pragma unroll
      for (int ns = 0; ns < 4; ++ns)
        acc[ms][ns] = MFMA16(a[ms], b[ns], acc[ms][ns]);
  }
}

// ---------------- pass1: symmetric row sums (upper-triangle blocks only) ----------------
__global__ __launch_bounds__(256) void rowsum_sym_kernel(
    const unsigned short* __restrict__ EH, const float* __restrict__ sq,
    float* __restrict__ rowsum)
{
  const int bi = blockIdx.y, bj = blockIdx.x;
  if (bj < bi) return;
  const int lane = threadIdx.x & 63;
  const int wave = threadIdx.x >> 6;
  const int wr = wave >> 1, wc = wave & 1;
  const int ibase = bi * 128 + wr * 64;
  const int jbase = bj * 128 + wc * 64;
  const int rl = lane & 15;
  const int rq = (lane >> 4) * 4;

  f32x4 zero = {0.f, 0.f, 0.f, 0.f};
  f32x4 acc[4][4];
#pragma unroll
  for (int ms = 0; ms < 4; ++ms)
#pragma unroll
    for (int ns = 0; ns < 4; ++ns) acc[ms][ns] = zero;
  dist_tile_hh(EH, ibase, jbase, lane, acc);

  float si[4][4], sj[4];
#pragma unroll
  for (int ms = 0; ms < 4; ++ms)
#pragma unroll
    for (int r = 0; r < 4; ++r) si[ms][r] = sq[ibase + ms * 16 + rq + r];
#pragma unroll
  for (int ns = 0; ns < 4; ++ns) sj[ns] = sq[jbase + ns * 16 + rl];

  float rs[4][4] = {};   // row partials (this lane's rl-slice)
  float cs[4]    = {};   // col partials (this lane's column, over its 4 quad-rows)
#pragma unroll
  for (int ms = 0; ms < 4; ++ms)
#pragma unroll
    for (int ns = 0; ns < 4; ++ns)
#pragma unroll
      for (int r = 0; r < 4; ++r) {
        float v = __expf(fmaf(2.f, acc[ms][ns][r], -si[ms][r] - sj[ns]));
        rs[ms][r] += v;
        cs[ns]    += v;
      }

  // row sums: reduce across rl within quad
#pragma unroll
  for (int ms = 0; ms < 4; ++ms)
#pragma unroll
    for (int r = 0; r < 4; ++r) {
      float v = rs[ms][r];
      v += __shfl_xor(v, 1, 64);
      v += __shfl_xor(v, 2, 64);
      v += __shfl_xor(v, 4, 64);
      v += __shfl_xor(v, 8, 64);
      if (rl == 0) atomicAdd(&rowsum[ibase + ms * 16 + rq + r], v);
    }

  // col sums (transposed contributions) only for off-diagonal blocks
  if (bi != bj) {
#pragma unroll
    for (int ns = 0; ns < 4; ++ns) {
      float v = cs[ns];
      v += __shfl_xor(v, 16, 64);
      v += __shfl_xor(v, 32, 64);
      if (lane < 16) atomicAdd(&rowsum[jbase + ns * 16 + rl], v);
    }
  }
}

// ---------------- pass2: full grid, recompute e, fully coalesced stores ----------------
__global__ __launch_bounds__(256) void dist_write_kernel(
    const unsigned short* __restrict__ EH, const float* __restrict__ sq,
    const float* __restrict__ rowsum, float* __restrict__ out)
{
  const int lane = threadIdx.x & 63;
  const int wave = threadIdx.x >> 6;
  const int wr = wave >> 1, wc = wave & 1;
  const int ibase = blockIdx.y * 128 + wr * 64;
  const int jbase = blockIdx.x * 128 + wc * 64;
  const int rl = lane & 15;
  const int rq = (lane >> 4) * 4;

  f32x4 zero = {0.f, 0.f, 0.f, 0.f};
  f32x4 acc[4][4];
#pragma unroll
  for (int ms = 0; ms < 4; ++ms)
#pragma unroll
    for (int ns = 0; ns < 4; ++ns) acc[ms][ns] = zero;
  dist_tile_hh(EH, ibase, jbase, lane, acc);

  float si[4][4], ri[4][4], sj[4];
#pragma unroll
  for (int ms = 0; ms < 4; ++ms)
#pragma unroll
    for (int r = 0; r < 4; ++r) {
      const int i = ibase + ms * 16 + rq + r;
      si[ms][r] = sq[i];
      ri[ms][r] = 1.f / rowsum[i];
    }
#pragma unroll
  for (int ns = 0; ns < 4; ++ns) sj[ns] = sq[jbase + ns * 16 + rl];

#pragma unroll
  for (int ms = 0; ms < 4; ++ms)
#pragma unroll
    for (int r = 0; r < 4; ++r) {
      const size_t row = (size_t)(ibase + ms * 16 + rq + r) * NN;
#pragma unroll
      for (int ns = 0; ns < 4; ++ns) {
        float e = __expf(fmaf(2.f, acc[ms][ns][r], -si[ms][r] - sj[ns]));
        out[row + jbase + ns * 16 + rl] = fmaf(e, ri[ms][r], 1e-10f);
      }
    }
}

// ---------------- launch ----------------
extern "C" void kernel_launch(void* const* d_in, const int* in_sizes, int n_in,
                              void* d_out, int out_size, void* d_ws, size_t ws_size,
                              hipStream_t stream)
{
  const float* X  = (const float*)d_in[0];
  const float* W1 = (const float*)d_in[1];
  const float* W2 = (const float*)d_in[2];
  const float* ev = (const float*)d_in[3];
  const int* esrc = (const int*)d_in[4];
  const int* edst = (const int*)d_in[5];
  float* out = (float*)d_out;

  char* p = (char*)d_ws;
  auto alloc = [&](size_t bytes) { char* q = p; p += (bytes + 255) & ~(size_t)255; return q; };

  // zero block first (single memset): counts, cursor, rowsum
  int*   counts    = (int*)alloc(NN * 4);
  int*   cursor    = (int*)alloc(NN * 4);
  float* rowsum    = (float*)alloc(NN * 4);
  int*   row_start = (int*)alloc((NN + 1) * 4);
  int*   csr_src   = (int*)alloc(NEDGE * 4);
  float* csr_val   = (float*)alloc(NEDGE * 4);
  float* sqv       = (float*)alloc(NN * 4);
  float* E1        = (float*)alloc((size_t)NN * DEMB * 4);
  unsigned short* W1b  = (unsigned short*)alloc((size_t)DMID * DIN * 2);
  unsigned short* W2b  = (unsigned short*)alloc((size_t)DEMB * DMID * 2);
  unsigned short* G1   = (unsigned short*)alloc((size_t)NN * DMID * 2);
  unsigned short* H1b  = (unsigned short*)alloc((size_t)NN * DMID * 2);
  unsigned short* EmbH = (unsigned short*)alloc((size_t)NN * DEMB * 2);

  hipMemsetAsync(d_ws, 0, (size_t)3 * NN * 4, stream);

  prep_kernel<<<WCONV_BLOCKS + NEDGE / 256, 256, 0, stream>>>(W1, W2, W1b, W2b, edst, counts);
  scan_kernel<<<1, 256, 0, stream>>>(counts, row_start);
  scatter_kernel<<<NEDGE / 256, 256, 0, stream>>>(esrc, ev, edst, row_start, cursor,
                                                  csr_src, csr_val);

  gemm1_kernel<<<dim3(DMID / 64, NN / 64), 256, 0, stream>>>(X, W1b, G1);
  spmm1_kernel<<<NN / 4, 256, 0, stream>>>(G1, row_start, csr_src, csr_val, H1b);
  gemm2_kernel<<<NN / 64, 256, 0, stream>>>(H1b, W2b, E1);
  spmm2_kernel<<<NN / 4, 256, 0, stream>>>(E1, row_start, csr_src, csr_val, EmbH, sqv);

  rowsum_sym_kernel<<<dim3(NN / 128, NN / 128), 256, 0, stream>>>(EmbH, sqv, rowsum);
  dist_write_kernel<<<dim3(NN / 128, NN / 128), 256, 0, stream>>>(EmbH, sqv, rowsum, out);
}